// Round 18
// baseline (503.322 us; speedup 1.0000x reference)
//
#include <hip/hip_runtime.h>
#include <hip/hip_bf16.h>
#include <stdint.h>

typedef __bf16 bf16_t;
typedef bf16_t bf16x8 __attribute__((ext_vector_type(8)));
typedef bf16_t bf16x4 __attribute__((ext_vector_type(4)));
typedef float f32x4 __attribute__((ext_vector_type(4)));

#define LOG2E 1.44269504088896340736f

// async global->LDS, 16B per lane. Dest must be linear (base + lane*16).
__device__ __forceinline__ void gld16(const void* g, void* l) {
  __builtin_amdgcn_global_load_lds(
      (__attribute__((address_space(1))) void*)(void*)(g),
      (__attribute__((address_space(3))) void*)(l), 16, 0, 0);
}

// XOR swizzle for 128B-row LDS tiles: spreads the 16B column slots across rows.
__device__ __forceinline__ int swz(int byteoff) {
  return byteoff ^ (((byteoff >> 7) & 7) << 4);
}

// ---------------- fp32 -> bf16 convert: weights only (4 x 1M elements) ------
__global__ __launch_bounds__(256) void cvt4_kernel(
    const float* __restrict__ s0, const float* __restrict__ s1,
    const float* __restrict__ s2, const float* __restrict__ s3,
    bf16_t* __restrict__ d0, bf16_t* __restrict__ d1,
    bf16_t* __restrict__ d2, bf16_t* __restrict__ d3) {
  const int t = blockIdx.x >> 7;
  const float* s = (t == 0) ? s0 : ((t == 1) ? s1 : ((t == 2) ? s2 : s3));
  bf16_t* d = (t == 0) ? d0 : ((t == 1) ? d1 : ((t == 2) ? d2 : d3));
  int i = (blockIdx.x & 127) * 256 + threadIdx.x;
#pragma unroll
  for (int u = 0; u < 8; ++u, i += 128 * 256) {
    const float4 v = reinterpret_cast<const float4*>(s)[i];
    bf16x4 o;
    o[0] = (bf16_t)v.x; o[1] = (bf16_t)v.y; o[2] = (bf16_t)v.z; o[3] = (bf16_t)v.w;
    reinterpret_cast<bf16x4*>(d)[i] = o;
  }
}

// ---------------- GEMM cores: BK=64, double-buffered LDS, 2-phase ----------
#define GBM 128
#define GBN 128
#define GBK 64

// bf16-A core (used by gemm_o). Identical to R14's proven gemm_core.
__device__ __forceinline__ void gemm_core(
    const bf16_t* __restrict__ A, const bf16_t* __restrict__ W,
    bf16_t* As, bf16_t* Bs, int m0, int n0, int K,
    int wm, int wn, int rr, int kk8, f32x4 acc[4][4]) {
  const int tid = threadIdx.x;
  const int t16 = tid * 16;
  int srow[4], scb[4];
#pragma unroll
  for (int i = 0; i < 4; ++i) {
    const int so = swz(i * 4096 + t16);
    srow[i] = so >> 7;
    scb[i] = so & 127;
  }
  const char* Ab = (const char*)A;
  const char* Wb = (const char*)W;
  const int nk = K / GBK;

#define GSTAGE(bufsel, kk0)                                                    \
  {                                                                            \
    char* Al = (char*)As + (bufsel) * 16384 + t16;                             \
    char* Bl = (char*)Bs + (bufsel) * 16384 + t16;                             \
    _Pragma("unroll")                                                          \
    for (int i = 0; i < 4; ++i) {                                              \
      gld16(Ab + ((size_t)(m0 + srow[i]) * K + (kk0)) * 2 + scb[i], Al + i * 4096); \
      gld16(Wb + ((size_t)(n0 + srow[i]) * K + (kk0)) * 2 + scb[i], Bl + i * 4096); \
    }                                                                          \
  }

  GSTAGE(0, 0)
  for (int t = 0; t < nk; ++t) {
    const int b = t & 1;
    asm volatile("s_waitcnt vmcnt(0)" ::: "memory");
    __builtin_amdgcn_s_barrier();
    __builtin_amdgcn_sched_barrier(0);
    GSTAGE(b ^ 1, ((t + 1) & (nk - 1)) * GBK)
    const char* Abl = (const char*)As + b * 16384;
    const char* Bbl = (const char*)Bs + b * 16384;
#pragma unroll
    for (int kk = 0; kk < 2; ++kk) {
      bf16x8 a[4], bb[4];
#pragma unroll
      for (int i = 0; i < 4; ++i)
        a[i] = *reinterpret_cast<const bf16x8*>(
            Abl + swz((wm + i * 16 + rr) * 128 + (kk * 32 + kk8) * 2));
#pragma unroll
      for (int i = 0; i < 4; ++i)
        bb[i] = *reinterpret_cast<const bf16x8*>(
            Bbl + swz((wn + i * 16 + rr) * 128 + (kk * 32 + kk8) * 2));
      __builtin_amdgcn_s_setprio(1);
#pragma unroll
      for (int i = 0; i < 4; ++i)
#pragma unroll
        for (int j = 0; j < 4; ++j)
          acc[i][j] = __builtin_amdgcn_mfma_f32_16x16x32_bf16(a[i], bb[j], acc[i][j], 0, 0, 0);
      __builtin_amdgcn_s_setprio(0);
    }
  }
#undef GSTAGE
}

// ---------------- fused Q/K/V projection GEMMs, fp32-A convert-on-stage ----
// v2: 2-deep A prefetch (fr[2]) + counted vmcnt(8) so cold-HBM fp32 A loads
// get TWO tiles of compute to land (R17 bug: 1 tile + vmcnt(0) exposed ~600
// cyc/tile). Issue order pinned B(t+1) then A(t+2): at iter top the 8 newest
// outstanding = A(t+1); vmcnt(8) drains {A(t), B(t)} only. Grid (n fast):
// 8 consecutive blocks share A rows -> L2/L3 absorbs re-reads.
__global__ __launch_bounds__(256) void gemm_qkv(
    const float* __restrict__ Xq, const float* __restrict__ Xk, const float* __restrict__ Xv,
    const bf16_t* __restrict__ Wq, const bf16_t* __restrict__ Wk, const bf16_t* __restrict__ Wv,
    const float* __restrict__ bq, const float* __restrict__ bk, const float* __restrict__ bv,
    bf16_t* __restrict__ Qo, bf16_t* __restrict__ Ko, bf16_t* __restrict__ Vo,
    int M, int N, int K) {
  const int z = blockIdx.z;
  const float* A = (z == 0) ? Xq : ((z == 1) ? Xk : Xv);
  const bf16_t* W = (z == 0) ? Wq : ((z == 1) ? Wk : Wv);
  const float* bias = (z == 0) ? bq : ((z == 1) ? bk : bv);
  bf16_t* Out = (z == 0) ? Qo : ((z == 1) ? Ko : Vo);

  __shared__ bf16_t As[2 * GBM * GBK];  // 32KB
  __shared__ bf16_t Bs[2 * GBN * GBK];  // 32KB
  const int tid = threadIdx.x;
  const int lane = tid & 63;
  const int w = tid >> 6;
  const int n0 = blockIdx.x * GBN;   // n FAST: consecutive blocks share A
  const int m0 = blockIdx.y * GBM;
  const int wm = (w >> 1) * 64;
  const int wn = (w & 1) * 64;
  const int rr = lane & 15;
  const int kk8 = (lane >> 4) * 8;

  // A staging geometry: thread covers bf16 bytes [tid*64, tid*64+64)
  int arow[4], acelt[4], asw[4];
#pragma unroll
  for (int j = 0; j < 4; ++j) {
    const int lin = tid * 64 + j * 16;
    asw[j] = swz(lin);
    arow[j] = lin >> 7;            // tile row 0..127
    acelt[j] = (lin & 127) >> 1;   // fp32 element offset within BK (mult of 8)
  }
  // B staging geometry (pre-swizzled source, linear gld16 dest)
  const int t16 = tid * 16;
  int srow[4], scb[4];
#pragma unroll
  for (int i = 0; i < 4; ++i) {
    const int so = swz(i * 4096 + t16);
    srow[i] = so >> 7;
    scb[i] = so & 127;
  }
  const char* Wb = (const char*)W;
  const int nk = K / GBK;  // 16

  float4 fr[2][8];
#define ALOAD(par, kk0)                                                        \
  {                                                                            \
    _Pragma("unroll")                                                          \
    for (int j = 0; j < 4; ++j) {                                              \
      const float* ap = A + (size_t)(m0 + arow[j]) * K + (kk0) + acelt[j];     \
      fr[par][2 * j] = *reinterpret_cast<const float4*>(ap);                   \
      fr[par][2 * j + 1] = *reinterpret_cast<const float4*>(ap + 4);           \
    }                                                                          \
  }
#define BSTAGE(bufsel, kk0)                                                    \
  {                                                                            \
    char* Bl = (char*)Bs + (bufsel) * 16384 + t16;                             \
    _Pragma("unroll")                                                          \
    for (int i = 0; i < 4; ++i)                                                \
      gld16(Wb + ((size_t)(n0 + srow[i]) * K + (kk0)) * 2 + scb[i], Bl + i * 4096); \
  }

  // prologue: A(0)->fr0 [8], B(0) [4], A(1)->fr1 [8]  (order pinned)
  ALOAD(0, 0)
  __builtin_amdgcn_sched_barrier(0);
  BSTAGE(0, 0)
  __builtin_amdgcn_sched_barrier(0);
  ALOAD(1, GBK)
  __builtin_amdgcn_sched_barrier(0);
  f32x4 acc[4][4] = {};

  for (int t = 0; t < nk; ++t) {
    const int b = t & 1;
    const int par = t & 1;
    // drain {A(t), B(t)}; leave A(t+1)'s 8 loads in flight
    asm volatile("s_waitcnt vmcnt(8)" ::: "memory");
    __builtin_amdgcn_s_barrier();       // buf b free for A-writes; B(t) visible
    __builtin_amdgcn_sched_barrier(0);
    // convert + write A(t) from fr[par] into buf b (swizzled dest)
#pragma unroll
    for (int j = 0; j < 4; ++j) {
      bf16x8 o;
      o[0] = (bf16_t)fr[par][2 * j].x; o[1] = (bf16_t)fr[par][2 * j].y;
      o[2] = (bf16_t)fr[par][2 * j].z; o[3] = (bf16_t)fr[par][2 * j].w;
      o[4] = (bf16_t)fr[par][2 * j + 1].x; o[5] = (bf16_t)fr[par][2 * j + 1].y;
      o[6] = (bf16_t)fr[par][2 * j + 1].z; o[7] = (bf16_t)fr[par][2 * j + 1].w;
      *reinterpret_cast<bf16x8*>((char*)As + b * 16384 + asw[j]) = o;
    }
    __builtin_amdgcn_sched_barrier(0);
    // issue B(t+1) then A(t+2) (fr[par] free after cvt above)
    BSTAGE(b ^ 1, ((t + 1) & (nk - 1)) * GBK)
    __builtin_amdgcn_sched_barrier(0);
    ALOAD(par, ((t + 2) & (nk - 1)) * GBK)
    __builtin_amdgcn_sched_barrier(0);
    asm volatile("s_waitcnt lgkmcnt(0)" ::: "memory");  // A(t) ds_writes done
    __builtin_amdgcn_s_barrier();                       // visible to all waves
    __builtin_amdgcn_sched_barrier(0);
    const char* Abl = (const char*)As + b * 16384;
    const char* Bbl = (const char*)Bs + b * 16384;
#pragma unroll
    for (int kk = 0; kk < 2; ++kk) {
      bf16x8 a[4], bb[4];
#pragma unroll
      for (int i = 0; i < 4; ++i)
        a[i] = *reinterpret_cast<const bf16x8*>(
            Abl + swz((wm + i * 16 + rr) * 128 + (kk * 32 + kk8) * 2));
#pragma unroll
      for (int i = 0; i < 4; ++i)
        bb[i] = *reinterpret_cast<const bf16x8*>(
            Bbl + swz((wn + i * 16 + rr) * 128 + (kk * 32 + kk8) * 2));
      __builtin_amdgcn_s_setprio(1);
#pragma unroll
      for (int i = 0; i < 4; ++i)
#pragma unroll
        for (int j = 0; j < 4; ++j)
          acc[i][j] = __builtin_amdgcn_mfma_f32_16x16x32_bf16(a[i], bb[j], acc[i][j], 0, 0, 0);
      __builtin_amdgcn_s_setprio(0);
    }
  }
#undef ALOAD
#undef BSTAGE

  const int rg = (lane >> 4) * 4;
#pragma unroll
  for (int i = 0; i < 4; ++i) {
#pragma unroll
    for (int j = 0; j < 4; ++j) {
      const int col = n0 + wn + j * 16 + rr;
      const float bi = bias[col];
      if (z == 2) {
        const int row0 = m0 + wm + i * 16 + rg;
        const int b_ = row0 >> 11, s_ = row0 & 2047;
        const int h_ = col >> 6, d_ = col & 63;
        const int k64 = s_ & 63;
        const int sl = (k64 & 32) | ((k64 & 12) << 1) | ((k64 & 16) >> 2);
        const int scol = (s_ & ~63) | sl;
        bf16x4 pack;
#pragma unroll
        for (int r = 0; r < 4; ++r) pack[r] = (bf16_t)(acc[i][j][r] + bi);
        *reinterpret_cast<bf16x4*>(&Out[((size_t)((b_ * 16 + h_) * 64 + d_)) * 2048 + scol]) = pack;
      } else {
        const float scale = (z == 0) ? (0.125f * LOG2E) : 1.0f;
#pragma unroll
        for (int r = 0; r < 4; ++r) {
          const int row = m0 + wm + i * 16 + rg + r;
          const int b_ = row >> 11, s_ = row & 2047;
          const int h_ = col >> 6, d_ = col & 63;
          Out[((size_t)((b_ * 16 + h_) * 2048 + s_)) * 64 + d_] = (bf16_t)((acc[i][j][r] + bi) * scale);
        }
      }
    }
  }
}

// ---------------- output projection GEMM: fp32 out ----------------
__global__ __launch_bounds__(256) void gemm_o(
    const bf16_t* __restrict__ A, const bf16_t* __restrict__ W,
    const float* __restrict__ bias, float* __restrict__ Out,
    int M, int N, int K) {
  __shared__ bf16_t As[2 * GBM * GBK];
  __shared__ bf16_t Bs[2 * GBN * GBK];
  const int tid = threadIdx.x;
  const int lane = tid & 63;
  const int w = tid >> 6;
  const int m0 = blockIdx.x * GBM;
  const int n0 = blockIdx.y * GBN;
  const int wm = (w >> 1) * 64;
  const int wn = (w & 1) * 64;
  const int rr = lane & 15;
  const int kk8 = (lane >> 4) * 8;

  f32x4 acc[4][4] = {};
  gemm_core(A, W, As, Bs, m0, n0, K, wm, wn, rr, kk8, acc);

  const int rg = (lane >> 4) * 4;
#pragma unroll
  for (int i = 0; i < 4; ++i)
#pragma unroll
    for (int j = 0; j < 4; ++j) {
      const int col = n0 + wn + j * 16 + rr;
      const float bi = bias[col];
#pragma unroll
      for (int r = 0; r < 4; ++r) {
        const int row = m0 + wm + i * 16 + rg + r;
        Out[(size_t)row * N + col] = acc[i][j][r] + bi;
      }
    }
}

// ---------------- flash attention with banded local bias ----------------
// v13 frozen (90.5us): v9 structure + __builtin_amdgcn_exp2f, (256,2) cap.
#define QT 256
#define KT 64

__global__ __launch_bounds__(256, 2) void attn_kernel(
    const bf16_t* __restrict__ Qg, const bf16_t* __restrict__ Kg,
    const bf16_t* __restrict__ Vtg, const float* __restrict__ lb,
    bf16_t* __restrict__ Og) {
  const int S = 2048;
  __shared__ bf16_t Qs[QT * 64];   // 32KB, swizzled (prologue only)
  __shared__ bf16_t Ks[KT * 64];   // 8KB, swizzled
  __shared__ bf16_t Vts[64 * KT];  // 8KB, swizzled (rows=d, cols=k-slots)
  __shared__ float lbs[33];

  const int tid = threadIdx.x, lane = tid & 63, w = tid >> 6;
  const int bh = blockIdx.x;          // fast dim -> same-bh blocks same XCD
  const int qt0 = blockIdx.y * QT;
  const int b_ = bh >> 4, h_ = bh & 15;

  const char* Qb = (const char*)(Qg + (size_t)bh * S * 64);
  const char* Kb = (const char*)(Kg + (size_t)bh * S * 64);
  const char* Vtb = (const char*)(Vtg + (size_t)bh * 64 * S);

  // stage Q tile: 32KB = 8 issues x 256 threads x 16B
#pragma unroll
  for (int i = 0; i < 8; ++i) {
    const int off = i * 4096 + tid * 16;
    gld16(Qb + (size_t)qt0 * 128 + swz(off), (char*)Qs + off);
  }
  if (tid < 33) lbs[tid] = lb[tid];

  // K/V reg staging (T14), write-side swizzle
  const int L0 = tid * 16;                   // 0..4095
  const int W0 = swz(L0), W1 = swz(L0 + 4096);
  const int vd0 = L0 >> 7, vcb = L0 & 127;
  int4 kr0, kr1, vr0, vr1;

#define LOADKV(t)                                                              \
  {                                                                            \
    const char* kp = Kb + (size_t)(t) * 8192;                                  \
    kr0 = *reinterpret_cast<const int4*>(kp + L0);                             \
    kr1 = *reinterpret_cast<const int4*>(kp + L0 + 4096);                      \
    const char* vp = Vtb + (size_t)(t) * 128;                                  \
    vr0 = *reinterpret_cast<const int4*>(vp + (size_t)vd0 * 4096 + vcb);       \
    vr1 = *reinterpret_cast<const int4*>(vp + (size_t)(vd0 + 32) * 4096 + vcb);\
  }
#define WRITEKV()                                                              \
  {                                                                            \
    *reinterpret_cast<int4*>((char*)Ks + W0) = kr0;                            \
    *reinterpret_cast<int4*>((char*)Ks + W1) = kr1;                            \
    *reinterpret_cast<int4*>((char*)Vts + W0) = vr0;                           \
    *reinterpret_cast<int4*>((char*)Vts + W1) = vr1;                           \
  }

  LOADKV(0)
  __syncthreads();  // Q staged (drains gld16)

  const int rr = lane & 15;
  const int kk8 = (lane >> 4) * 8;
  const int rg = (lane >> 4) * 4;

  bf16x8 qf[4][2];  // wave w owns q rows [w*64, w*64+64)
#pragma unroll
  for (int qg = 0; qg < 4; ++qg)
#pragma unroll
    for (int kk = 0; kk < 2; ++kk) {
      const int off = (w * 64 + qg * 16 + rr) * 128 + (kk * 32 + kk8) * 2;
      qf[qg][kk] = *reinterpret_cast<const bf16x8*>((const char*)Qs + swz(off));
    }

  f32x4 oacc[4][4] = {};
  float lrowp[4] = {0.f, 0.f, 0.f, 0.f};

  for (int kt = 0; kt < S / KT; ++kt) {
    // commit staged tile kt (regs loaded last iter, drained at last barrier)
    WRITEKV()
    __syncthreads();  // tile kt visible
    // prefetch tile kt+1: issued AFTER the barrier -> overlaps compute,
    // drained by the end-of-iteration barrier's vmcnt(0)
    LOADKV((kt + 1) & 31)

    bf16x8 kf[4][2];
#pragma unroll
    for (int ni = 0; ni < 4; ++ni)
#pragma unroll
      for (int kk = 0; kk < 2; ++kk) {
        const int off = (ni * 16 + rr) * 128 + (kk * 32 + kk8) * 2;
        kf[ni][kk] = *reinterpret_cast<const bf16x8*>((const char*)Ks + swz(off));
      }
    bf16x8 vf[2][4];
#pragma unroll
    for (int kk = 0; kk < 2; ++kk)
#pragma unroll
      for (int nd = 0; nd < 4; ++nd) {
        const int off = (nd * 16 + rr) * 128 + (kk * 32 + kk8) * 2;
        vf[kk][nd] = *reinterpret_cast<const bf16x8*>((const char*)Vts + swz(off));
      }

    const int kbase = kt * KT;
#pragma unroll
    for (int qg = 0; qg < 4; ++qg) {
      // QK^T (swapped): lane holds q = w*64 + qg*16 + rr; k = 16ni + 4hi + r
      f32x4 sc[4];
      __builtin_amdgcn_s_setprio(1);
#pragma unroll
      for (int ni = 0; ni < 4; ++ni) {
        f32x4 z = {0.f, 0.f, 0.f, 0.f};
#pragma unroll
        for (int kk = 0; kk < 2; ++kk)
          z = __builtin_amdgcn_mfma_f32_16x16x32_bf16(kf[ni][kk], qf[qg][kk], z, 0, 0, 0);
        sc[ni] = z;
      }
      __builtin_amdgcn_s_setprio(0);

      // banded local bias (exp2 domain); wave-uniform guard per qg
      const int qlo = qt0 + w * 64 + qg * 16;
      if (kbase + KT + 16 > qlo && kbase < qlo + 16 + 16) {
        const int q = qlo + rr;
#pragma unroll
        for (int ni = 0; ni < 4; ++ni)
#pragma unroll
          for (int r = 0; r < 4; ++r) {
            const int rel = (kbase + ni * 16 + rg + r) - q;
            if (rel >= -16 && rel <= 16)
              sc[ni][r] += (2.0f * LOG2E) * lbs[rel + 16];
          }
      }

      // softmax (no max subtraction; scores bounded) + PV A-frags in-register
      bf16x8 paf[2];
      float ps0 = 0.f, ps1 = 0.f;
#pragma unroll
      for (int ni = 0; ni < 4; ++ni) {
        const float p0 = __builtin_amdgcn_exp2f(sc[ni][0]);
        const float p1 = __builtin_amdgcn_exp2f(sc[ni][1]);
        const float p2 = __builtin_amdgcn_exp2f(sc[ni][2]);
        const float p3 = __builtin_amdgcn_exp2f(sc[ni][3]);
        ps0 += p0 + p2;
        ps1 += p1 + p3;
        paf[ni >> 1][(ni & 1) * 4 + 0] = (bf16_t)p0;
        paf[ni >> 1][(ni & 1) * 4 + 1] = (bf16_t)p1;
        paf[ni >> 1][(ni & 1) * 4 + 2] = (bf16_t)p2;
        paf[ni >> 1][(ni & 1) * 4 + 3] = (bf16_t)p3;
      }
      lrowp[qg] += ps0 + ps1;

      // PV (V slot-permuted to match A-frag slots)
      __builtin_amdgcn_s_setprio(1);
#pragma unroll
      for (int kk = 0; kk < 2; ++kk)
#pragma unroll
        for (int nd = 0; nd < 4; ++nd)
          oacc[qg][nd] = __builtin_amdgcn_mfma_f32_16x16x32_bf16(paf[kk], vf[kk][nd], oacc[qg][nd], 0, 0, 0);
      __builtin_amdgcn_s_setprio(0);
    }
    __syncthreads();  // readers done with Ks/Vts; prefetch loads drained
  }

  // epilogue
#pragma unroll
  for (int qg = 0; qg < 4; ++qg) {
    float t = lrowp[qg];
    t += __shfl_xor(t, 16, 64);
    t += __shfl_xor(t, 32, 64);
    float lf[4];
#pragma unroll
    for (int r = 0; r < 4; ++r)
      lf[r] = __shfl(t, (lane & 48) | (rg + r), 64);
#pragma unroll
    for (int nd = 0; nd < 4; ++nd)
#pragma unroll
      for (int r = 0; r < 4; ++r) {
        const int srow = qt0 + w * 64 + qg * 16 + rg + r;
        const int d = nd * 16 + rr;
        const float v = oacc[qg][nd][r] / lf[r];
        Og[((size_t)(b_ * 2048 + srow)) * 1024 + h_ * 64 + d] = (bf16_t)v;
      }
  }
}

// ---------------- launch ----------------
extern "C" void kernel_launch(void* const* d_in, const int* in_sizes, int n_in,
                              void* d_out, int out_size, void* d_ws, size_t ws_size,
                              hipStream_t stream) {
  const float* q32 = (const float*)d_in[0];
  const float* k32 = (const float*)d_in[1];
  const float* v32 = (const float*)d_in[2];
  const float* wq = (const float*)d_in[3];
  const float* bq = (const float*)d_in[4];
  const float* wk = (const float*)d_in[5];
  const float* bk = (const float*)d_in[6];
  const float* wv = (const float*)d_in[7];
  const float* bv = (const float*)d_in[8];
  const float* wo = (const float*)d_in[9];
  const float* bo = (const float*)d_in[10];
  const float* lb = (const float*)d_in[11];

  const int M = 8192, N = 1024, K = 1024;
  const size_t REG = (size_t)M * N * 2;

  char* ws = (char*)d_ws;
  bf16_t* Qb = (bf16_t*)(ws + 0 * REG);
  bf16_t* Kb = (bf16_t*)(ws + 1 * REG);
  bf16_t* Vt = (bf16_t*)(ws + 2 * REG);
  bf16_t* attn = (bf16_t*)(ws + 3 * REG);
  bf16_t* Wqb = (bf16_t*)(ws + 4 * REG);
  bf16_t* Wkb = Wqb + (size_t)N * K;
  bf16_t* Wvb = Wkb + (size_t)N * K;
  bf16_t* Wob = Wvb + (size_t)N * K;

  cvt4_kernel<<<dim3(512), dim3(256), 0, stream>>>(
      wq, wk, wv, wo, Wqb, Wkb, Wvb, Wob);

  gemm_qkv<<<dim3(N / GBN, M / GBM, 3), 256, 0, stream>>>(
      q32, k32, v32, Wqb, Wkb, Wvb, bq, bk, bv, Qb, Kb, Vt, M, N, K);

  attn_kernel<<<dim3(64, 2048 / QT), 256, 0, stream>>>(Qb, Kb, Vt, lb, attn);

  gemm_o<<<dim3(M / GBM, N / GBN), 256, 0, stream>>>(attn, Wob, bo, (float*)d_out, M, N, K);
}

// Round 19
// 269.883 us; speedup vs baseline: 1.8650x; 1.8650x over previous
//
#include <hip/hip_runtime.h>
#include <hip/hip_bf16.h>
#include <stdint.h>

typedef __bf16 bf16_t;
typedef bf16_t bf16x8 __attribute__((ext_vector_type(8)));
typedef bf16_t bf16x4 __attribute__((ext_vector_type(4)));
typedef float f32x4 __attribute__((ext_vector_type(4)));

#define LOG2E 1.44269504088896340736f

// async global->LDS, 16B per lane. Dest must be linear (base + lane*16).
__device__ __forceinline__ void gld16(const void* g, void* l) {
  __builtin_amdgcn_global_load_lds(
      (__attribute__((address_space(1))) void*)(void*)(g),
      (__attribute__((address_space(3))) void*)(l), 16, 0, 0);
}

// XOR swizzle for 128B-row LDS tiles: spreads the 16B column slots across rows.
__device__ __forceinline__ int swz(int byteoff) {
  return byteoff ^ (((byteoff >> 7) & 7) << 4);
}

// ---------------- fp32 -> bf16 convert: weights only (4 x 1M elements) ------
__global__ __launch_bounds__(256) void cvt4_kernel(
    const float* __restrict__ s0, const float* __restrict__ s1,
    const float* __restrict__ s2, const float* __restrict__ s3,
    bf16_t* __restrict__ d0, bf16_t* __restrict__ d1,
    bf16_t* __restrict__ d2, bf16_t* __restrict__ d3) {
  const int t = blockIdx.x >> 7;
  const float* s = (t == 0) ? s0 : ((t == 1) ? s1 : ((t == 2) ? s2 : s3));
  bf16_t* d = (t == 0) ? d0 : ((t == 1) ? d1 : ((t == 2) ? d2 : d3));
  int i = (blockIdx.x & 127) * 256 + threadIdx.x;
#pragma unroll
  for (int u = 0; u < 8; ++u, i += 128 * 256) {
    const float4 v = reinterpret_cast<const float4*>(s)[i];
    bf16x4 o;
    o[0] = (bf16_t)v.x; o[1] = (bf16_t)v.y; o[2] = (bf16_t)v.z; o[3] = (bf16_t)v.w;
    reinterpret_cast<bf16x4*>(d)[i] = o;
  }
}

// ---------------- GEMM cores: BK=64, double-buffered LDS, 2-phase ----------
#define GBM 128
#define GBN 128
#define GBK 64

// bf16-A core (used by gemm_o). Identical to R14's proven gemm_core.
__device__ __forceinline__ void gemm_core(
    const bf16_t* __restrict__ A, const bf16_t* __restrict__ W,
    bf16_t* As, bf16_t* Bs, int m0, int n0, int K,
    int wm, int wn, int rr, int kk8, f32x4 acc[4][4]) {
  const int tid = threadIdx.x;
  const int t16 = tid * 16;
  int srow[4], scb[4];
#pragma unroll
  for (int i = 0; i < 4; ++i) {
    const int so = swz(i * 4096 + t16);
    srow[i] = so >> 7;
    scb[i] = so & 127;
  }
  const char* Ab = (const char*)A;
  const char* Wb = (const char*)W;
  const int nk = K / GBK;

#define GSTAGE(bufsel, kk0)                                                    \
  {                                                                            \
    char* Al = (char*)As + (bufsel) * 16384 + t16;                             \
    char* Bl = (char*)Bs + (bufsel) * 16384 + t16;                             \
    _Pragma("unroll")                                                          \
    for (int i = 0; i < 4; ++i) {                                              \
      gld16(Ab + ((size_t)(m0 + srow[i]) * K + (kk0)) * 2 + scb[i], Al + i * 4096); \
      gld16(Wb + ((size_t)(n0 + srow[i]) * K + (kk0)) * 2 + scb[i], Bl + i * 4096); \
    }                                                                          \
  }

  GSTAGE(0, 0)
  for (int t = 0; t < nk; ++t) {
    const int b = t & 1;
    asm volatile("s_waitcnt vmcnt(0)" ::: "memory");
    __builtin_amdgcn_s_barrier();
    __builtin_amdgcn_sched_barrier(0);
    GSTAGE(b ^ 1, ((t + 1) & (nk - 1)) * GBK)
    const char* Abl = (const char*)As + b * 16384;
    const char* Bbl = (const char*)Bs + b * 16384;
#pragma unroll
    for (int kk = 0; kk < 2; ++kk) {
      bf16x8 a[4], bb[4];
#pragma unroll
      for (int i = 0; i < 4; ++i)
        a[i] = *reinterpret_cast<const bf16x8*>(
            Abl + swz((wm + i * 16 + rr) * 128 + (kk * 32 + kk8) * 2));
#pragma unroll
      for (int i = 0; i < 4; ++i)
        bb[i] = *reinterpret_cast<const bf16x8*>(
            Bbl + swz((wn + i * 16 + rr) * 128 + (kk * 32 + kk8) * 2));
      __builtin_amdgcn_s_setprio(1);
#pragma unroll
      for (int i = 0; i < 4; ++i)
#pragma unroll
        for (int j = 0; j < 4; ++j)
          acc[i][j] = __builtin_amdgcn_mfma_f32_16x16x32_bf16(a[i], bb[j], acc[i][j], 0, 0, 0);
      __builtin_amdgcn_s_setprio(0);
    }
  }
#undef GSTAGE
}

// ---------------- fused Q/K/V projection GEMMs, fp32-A convert-on-stage ----
// v3: R18's 2-deep A prefetch + counted vmcnt(8), with the rule-#20 fix:
// K-loop unrolled by TWO with NAMED register buffers frA/frB (all indices
// compile-time constant -> registers, not scratch). R18's fr[2][8][t&1]
// runtime index sent the prefetch array to local memory (WRITE_SIZE 935MB).
// Schedule per body: vmcnt(8) {drains A(t),B(t); A(t+1) stays in flight} ->
// barrier -> cvt FR->LDS buf b -> BSTAGE(t+1) -> ALOAD(FR, t+2) ->
// lgkmcnt(0) -> barrier -> ds_read+MFMA. Grid n-fast: 8 blocks share A rows.
__global__ __launch_bounds__(256) void gemm_qkv(
    const float* __restrict__ Xq, const float* __restrict__ Xk, const float* __restrict__ Xv,
    const bf16_t* __restrict__ Wq, const bf16_t* __restrict__ Wk, const bf16_t* __restrict__ Wv,
    const float* __restrict__ bq, const float* __restrict__ bk, const float* __restrict__ bv,
    bf16_t* __restrict__ Qo, bf16_t* __restrict__ Ko, bf16_t* __restrict__ Vo,
    int M, int N, int K) {
  const int z = blockIdx.z;
  const float* A = (z == 0) ? Xq : ((z == 1) ? Xk : Xv);
  const bf16_t* W = (z == 0) ? Wq : ((z == 1) ? Wk : Wv);
  const float* bias = (z == 0) ? bq : ((z == 1) ? bk : bv);
  bf16_t* Out = (z == 0) ? Qo : ((z == 1) ? Ko : Vo);

  __shared__ bf16_t As[2 * GBM * GBK];  // 32KB
  __shared__ bf16_t Bs[2 * GBN * GBK];  // 32KB
  const int tid = threadIdx.x;
  const int lane = tid & 63;
  const int w = tid >> 6;
  const int n0 = blockIdx.x * GBN;   // n FAST: consecutive blocks share A
  const int m0 = blockIdx.y * GBM;
  const int wm = (w >> 1) * 64;
  const int wn = (w & 1) * 64;
  const int rr = lane & 15;
  const int kk8 = (lane >> 4) * 8;

  // A staging geometry: thread covers bf16 bytes [tid*64, tid*64+64)
  int arow[4], acelt[4], asw[4];
#pragma unroll
  for (int j = 0; j < 4; ++j) {
    const int lin = tid * 64 + j * 16;
    asw[j] = swz(lin);
    arow[j] = lin >> 7;            // tile row 0..127
    acelt[j] = (lin & 127) >> 1;   // fp32 element offset within BK (mult of 8)
  }
  // B staging geometry (pre-swizzled source, linear gld16 dest)
  const int t16 = tid * 16;
  int srow[4], scb[4];
#pragma unroll
  for (int i = 0; i < 4; ++i) {
    const int so = swz(i * 4096 + t16);
    srow[i] = so >> 7;
    scb[i] = so & 127;
  }
  const char* Wb = (const char*)W;
  const int nk = K / GBK;  // 16

  float4 frA[8], frB[8];  // named, statically indexed (rule #20)

#define ALOAD(FR, kk0)                                                         \
  {                                                                            \
    _Pragma("unroll")                                                          \
    for (int j = 0; j < 4; ++j) {                                              \
      const float* ap = A + (size_t)(m0 + arow[j]) * K + (kk0) + acelt[j];     \
      FR[2 * j] = *reinterpret_cast<const float4*>(ap);                        \
      FR[2 * j + 1] = *reinterpret_cast<const float4*>(ap + 4);                \
    }                                                                          \
  }
#define BSTAGE(bufsel, kk0)                                                    \
  {                                                                            \
    char* Bl = (char*)Bs + (bufsel) * 16384 + t16;                             \
    _Pragma("unroll")                                                          \
    for (int i = 0; i < 4; ++i)                                                \
      gld16(Wb + ((size_t)(n0 + srow[i]) * K + (kk0)) * 2 + scb[i], Bl + i * 4096); \
  }
// One pipeline body: tile tc uses FR (regs), LDS buf BUFSEL; prefetches
// B(tc+1) into buf BUFSEL^1 and A(tc+2) into FR (same parity -> same buffer).
#define GBODY(tc, FR, BUFSEL)                                                  \
  {                                                                            \
    asm volatile("s_waitcnt vmcnt(8)" ::: "memory");                           \
    __builtin_amdgcn_s_barrier();                                              \
    __builtin_amdgcn_sched_barrier(0);                                         \
    _Pragma("unroll")                                                          \
    for (int j = 0; j < 4; ++j) {                                              \
      bf16x8 o;                                                                \
      o[0] = (bf16_t)FR[2 * j].x; o[1] = (bf16_t)FR[2 * j].y;                  \
      o[2] = (bf16_t)FR[2 * j].z; o[3] = (bf16_t)FR[2 * j].w;                  \
      o[4] = (bf16_t)FR[2 * j + 1].x; o[5] = (bf16_t)FR[2 * j + 1].y;          \
      o[6] = (bf16_t)FR[2 * j + 1].z; o[7] = (bf16_t)FR[2 * j + 1].w;          \
      *reinterpret_cast<bf16x8*>((char*)As + (BUFSEL) * 16384 + asw[j]) = o;   \
    }                                                                          \
    __builtin_amdgcn_sched_barrier(0);                                         \
    BSTAGE((BUFSEL) ^ 1, (((tc) + 1) & (nk - 1)) * GBK)                        \
    __builtin_amdgcn_sched_barrier(0);                                         \
    ALOAD(FR, (((tc) + 2) & (nk - 1)) * GBK)                                   \
    __builtin_amdgcn_sched_barrier(0);                                         \
    asm volatile("s_waitcnt lgkmcnt(0)" ::: "memory");                         \
    __builtin_amdgcn_s_barrier();                                              \
    __builtin_amdgcn_sched_barrier(0);                                         \
    const char* Abl = (const char*)As + (BUFSEL) * 16384;                      \
    const char* Bbl = (const char*)Bs + (BUFSEL) * 16384;                      \
    _Pragma("unroll")                                                          \
    for (int kk = 0; kk < 2; ++kk) {                                           \
      bf16x8 a[4], bb[4];                                                      \
      _Pragma("unroll")                                                        \
      for (int i = 0; i < 4; ++i)                                              \
        a[i] = *reinterpret_cast<const bf16x8*>(                               \
            Abl + swz((wm + i * 16 + rr) * 128 + (kk * 32 + kk8) * 2));        \
      _Pragma("unroll")                                                        \
      for (int i = 0; i < 4; ++i)                                              \
        bb[i] = *reinterpret_cast<const bf16x8*>(                              \
            Bbl + swz((wn + i * 16 + rr) * 128 + (kk * 32 + kk8) * 2));        \
      __builtin_amdgcn_s_setprio(1);                                           \
      _Pragma("unroll")                                                        \
      for (int i = 0; i < 4; ++i)                                              \
        _Pragma("unroll")                                                      \
        for (int j = 0; j < 4; ++j)                                            \
          acc[i][j] = __builtin_amdgcn_mfma_f32_16x16x32_bf16(a[i], bb[j], acc[i][j], 0, 0, 0); \
      __builtin_amdgcn_s_setprio(0);                                           \
    }                                                                          \
  }

  // prologue: A(0)->frA [8], B(0)->buf0 [4], A(1)->frB [8] (order pinned)
  ALOAD(frA, 0)
  __builtin_amdgcn_sched_barrier(0);
  BSTAGE(0, 0)
  __builtin_amdgcn_sched_barrier(0);
  ALOAD(frB, GBK)
  __builtin_amdgcn_sched_barrier(0);
  f32x4 acc[4][4] = {};

  for (int t = 0; t < nk; t += 2) {
    GBODY(t, frA, 0)
    GBODY(t + 1, frB, 1)
  }
#undef GBODY
#undef ALOAD
#undef BSTAGE

  const int rg = (lane >> 4) * 4;
#pragma unroll
  for (int i = 0; i < 4; ++i) {
#pragma unroll
    for (int j = 0; j < 4; ++j) {
      const int col = n0 + wn + j * 16 + rr;
      const float bi = bias[col];
      if (z == 2) {
        const int row0 = m0 + wm + i * 16 + rg;
        const int b_ = row0 >> 11, s_ = row0 & 2047;
        const int h_ = col >> 6, d_ = col & 63;
        const int k64 = s_ & 63;
        const int sl = (k64 & 32) | ((k64 & 12) << 1) | ((k64 & 16) >> 2);
        const int scol = (s_ & ~63) | sl;
        bf16x4 pack;
#pragma unroll
        for (int r = 0; r < 4; ++r) pack[r] = (bf16_t)(acc[i][j][r] + bi);
        *reinterpret_cast<bf16x4*>(&Out[((size_t)((b_ * 16 + h_) * 64 + d_)) * 2048 + scol]) = pack;
      } else {
        const float scale = (z == 0) ? (0.125f * LOG2E) : 1.0f;
#pragma unroll
        for (int r = 0; r < 4; ++r) {
          const int row = m0 + wm + i * 16 + rg + r;
          const int b_ = row >> 11, s_ = row & 2047;
          const int h_ = col >> 6, d_ = col & 63;
          Out[((size_t)((b_ * 16 + h_) * 2048 + s_)) * 64 + d_] = (bf16_t)((acc[i][j][r] + bi) * scale);
        }
      }
    }
  }
}

// ---------------- output projection GEMM: fp32 out ----------------
__global__ __launch_bounds__(256) void gemm_o(
    const bf16_t* __restrict__ A, const bf16_t* __restrict__ W,
    const float* __restrict__ bias, float* __restrict__ Out,
    int M, int N, int K) {
  __shared__ bf16_t As[2 * GBM * GBK];
  __shared__ bf16_t Bs[2 * GBN * GBK];
  const int tid = threadIdx.x;
  const int lane = tid & 63;
  const int w = tid >> 6;
  const int m0 = blockIdx.x * GBM;
  const int n0 = blockIdx.y * GBN;
  const int wm = (w >> 1) * 64;
  const int wn = (w & 1) * 64;
  const int rr = lane & 15;
  const int kk8 = (lane >> 4) * 8;

  f32x4 acc[4][4] = {};
  gemm_core(A, W, As, Bs, m0, n0, K, wm, wn, rr, kk8, acc);

  const int rg = (lane >> 4) * 4;
#pragma unroll
  for (int i = 0; i < 4; ++i)
#pragma unroll
    for (int j = 0; j < 4; ++j) {
      const int col = n0 + wn + j * 16 + rr;
      const float bi = bias[col];
#pragma unroll
      for (int r = 0; r < 4; ++r) {
        const int row = m0 + wm + i * 16 + rg + r;
        Out[(size_t)row * N + col] = acc[i][j][r] + bi;
      }
    }
}

// ---------------- flash attention with banded local bias ----------------
// v13 frozen (90.5us): v9 structure + __builtin_amdgcn_exp2f, (256,2) cap.
#define QT 256
#define KT 64

__global__ __launch_bounds__(256, 2) void attn_kernel(
    const bf16_t* __restrict__ Qg, const bf16_t* __restrict__ Kg,
    const bf16_t* __restrict__ Vtg, const float* __restrict__ lb,
    bf16_t* __restrict__ Og) {
  const int S = 2048;
  __shared__ bf16_t Qs[QT * 64];   // 32KB, swizzled (prologue only)
  __shared__ bf16_t Ks[KT * 64];   // 8KB, swizzled
  __shared__ bf16_t Vts[64 * KT];  // 8KB, swizzled (rows=d, cols=k-slots)
  __shared__ float lbs[33];

  const int tid = threadIdx.x, lane = tid & 63, w = tid >> 6;
  const int bh = blockIdx.x;          // fast dim -> same-bh blocks same XCD
  const int qt0 = blockIdx.y * QT;
  const int b_ = bh >> 4, h_ = bh & 15;

  const char* Qb = (const char*)(Qg + (size_t)bh * S * 64);
  const char* Kb = (const char*)(Kg + (size_t)bh * S * 64);
  const char* Vtb = (const char*)(Vtg + (size_t)bh * 64 * S);

  // stage Q tile: 32KB = 8 issues x 256 threads x 16B
#pragma unroll
  for (int i = 0; i < 8; ++i) {
    const int off = i * 4096 + tid * 16;
    gld16(Qb + (size_t)qt0 * 128 + swz(off), (char*)Qs + off);
  }
  if (tid < 33) lbs[tid] = lb[tid];

  // K/V reg staging (T14), write-side swizzle
  const int L0 = tid * 16;                   // 0..4095
  const int W0 = swz(L0), W1 = swz(L0 + 4096);
  const int vd0 = L0 >> 7, vcb = L0 & 127;
  int4 kr0, kr1, vr0, vr1;

#define LOADKV(t)                                                              \
  {                                                                            \
    const char* kp = Kb + (size_t)(t) * 8192;                                  \
    kr0 = *reinterpret_cast<const int4*>(kp + L0);                             \
    kr1 = *reinterpret_cast<const int4*>(kp + L0 + 4096);                      \
    const char* vp = Vtb + (size_t)(t) * 128;                                  \
    vr0 = *reinterpret_cast<const int4*>(vp + (size_t)vd0 * 4096 + vcb);       \
    vr1 = *reinterpret_cast<const int4*>(vp + (size_t)(vd0 + 32) * 4096 + vcb);\
  }
#define WRITEKV()                                                              \
  {                                                                            \
    *reinterpret_cast<int4*>((char*)Ks + W0) = kr0;                            \
    *reinterpret_cast<int4*>((char*)Ks + W1) = kr1;                            \
    *reinterpret_cast<int4*>((char*)Vts + W0) = vr0;                           \
    *reinterpret_cast<int4*>((char*)Vts + W1) = vr1;                           \
  }

  LOADKV(0)
  __syncthreads();  // Q staged (drains gld16)

  const int rr = lane & 15;
  const int kk8 = (lane >> 4) * 8;
  const int rg = (lane >> 4) * 4;

  bf16x8 qf[4][2];  // wave w owns q rows [w*64, w*64+64)
#pragma unroll
  for (int qg = 0; qg < 4; ++qg)
#pragma unroll
    for (int kk = 0; kk < 2; ++kk) {
      const int off = (w * 64 + qg * 16 + rr) * 128 + (kk * 32 + kk8) * 2;
      qf[qg][kk] = *reinterpret_cast<const bf16x8*>((const char*)Qs + swz(off));
    }

  f32x4 oacc[4][4] = {};
  float lrowp[4] = {0.f, 0.f, 0.f, 0.f};

  for (int kt = 0; kt < S / KT; ++kt) {
    // commit staged tile kt (regs loaded last iter, drained at last barrier)
    WRITEKV()
    __syncthreads();  // tile kt visible
    // prefetch tile kt+1: issued AFTER the barrier -> overlaps compute,
    // drained by the end-of-iteration barrier's vmcnt(0)
    LOADKV((kt + 1) & 31)

    bf16x8 kf[4][2];
#pragma unroll
    for (int ni = 0; ni < 4; ++ni)
#pragma unroll
      for (int kk = 0; kk < 2; ++kk) {
        const int off = (ni * 16 + rr) * 128 + (kk * 32 + kk8) * 2;
        kf[ni][kk] = *reinterpret_cast<const bf16x8*>((const char*)Ks + swz(off));
      }
    bf16x8 vf[2][4];
#pragma unroll
    for (int kk = 0; kk < 2; ++kk)
#pragma unroll
      for (int nd = 0; nd < 4; ++nd) {
        const int off = (nd * 16 + rr) * 128 + (kk * 32 + kk8) * 2;
        vf[kk][nd] = *reinterpret_cast<const bf16x8*>((const char*)Vts + swz(off));
      }

    const int kbase = kt * KT;
#pragma unroll
    for (int qg = 0; qg < 4; ++qg) {
      // QK^T (swapped): lane holds q = w*64 + qg*16 + rr; k = 16ni + 4hi + r
      f32x4 sc[4];
      __builtin_amdgcn_s_setprio(1);
#pragma unroll
      for (int ni = 0; ni < 4; ++ni) {
        f32x4 z = {0.f, 0.f, 0.f, 0.f};
#pragma unroll
        for (int kk = 0; kk < 2; ++kk)
          z = __builtin_amdgcn_mfma_f32_16x16x32_bf16(kf[ni][kk], qf[qg][kk], z, 0, 0, 0);
        sc[ni] = z;
      }
      __builtin_amdgcn_s_setprio(0);

      // banded local bias (exp2 domain); wave-uniform guard per qg
      const int qlo = qt0 + w * 64 + qg * 16;
      if (kbase + KT + 16 > qlo && kbase < qlo + 16 + 16) {
        const int q = qlo + rr;
#pragma unroll
        for (int ni = 0; ni < 4; ++ni)
#pragma unroll
          for (int r = 0; r < 4; ++r) {
            const int rel = (kbase + ni * 16 + rg + r) - q;
            if (rel >= -16 && rel <= 16)
              sc[ni][r] += (2.0f * LOG2E) * lbs[rel + 16];
          }
      }

      // softmax (no max subtraction; scores bounded) + PV A-frags in-register
      bf16x8 paf[2];
      float ps0 = 0.f, ps1 = 0.f;
#pragma unroll
      for (int ni = 0; ni < 4; ++ni) {
        const float p0 = __builtin_amdgcn_exp2f(sc[ni][0]);
        const float p1 = __builtin_amdgcn_exp2f(sc[ni][1]);
        const float p2 = __builtin_amdgcn_exp2f(sc[ni][2]);
        const float p3 = __builtin_amdgcn_exp2f(sc[ni][3]);
        ps0 += p0 + p2;
        ps1 += p1 + p3;
        paf[ni >> 1][(ni & 1) * 4 + 0] = (bf16_t)p0;
        paf[ni >> 1][(ni & 1) * 4 + 1] = (bf16_t)p1;
        paf[ni >> 1][(ni & 1) * 4 + 2] = (bf16_t)p2;
        paf[ni >> 1][(ni & 1) * 4 + 3] = (bf16_t)p3;
      }
      lrowp[qg] += ps0 + ps1;

      // PV (V slot-permuted to match A-frag slots)
      __builtin_amdgcn_s_setprio(1);
#pragma unroll
      for (int kk = 0; kk < 2; ++kk)
#pragma unroll
        for (int nd = 0; nd < 4; ++nd)
          oacc[qg][nd] = __builtin_amdgcn_mfma_f32_16x16x32_bf16(paf[kk], vf[kk][nd], oacc[qg][nd], 0, 0, 0);
      __builtin_amdgcn_s_setprio(0);
    }
    __syncthreads();  // readers done with Ks/Vts; prefetch loads drained
  }

  // epilogue
#pragma unroll
  for (int qg = 0; qg < 4; ++qg) {
    float t = lrowp[qg];
    t += __shfl_xor(t, 16, 64);
    t += __shfl_xor(t, 32, 64);
    float lf[4];
#pragma unroll
    for (int r = 0; r < 4; ++r)
      lf[r] = __shfl(t, (lane & 48) | (rg + r), 64);
#pragma unroll
    for (int nd = 0; nd < 4; ++nd)
#pragma unroll
      for (int r = 0; r < 4; ++r) {
        const int srow = qt0 + w * 64 + qg * 16 + rg + r;
        const int d = nd * 16 + rr;
        const float v = oacc[qg][nd][r] / lf[r];
        Og[((size_t)(b_ * 2048 + srow)) * 1024 + h_ * 64 + d] = (bf16_t)v;
      }
  }
}

// ---------------- launch ----------------
extern "C" void kernel_launch(void* const* d_in, const int* in_sizes, int n_in,
                              void* d_out, int out_size, void* d_ws, size_t ws_size,
                              hipStream_t stream) {
  const float* q32 = (const float*)d_in[0];
  const float* k32 = (const float*)d_in[1];
  const float* v32 = (const float*)d_in[2];
  const float* wq = (const float*)d_in[3];
  const float* bq = (const float*)d_in[4];
  const float* wk = (const float*)d_in[5];
  const float* bk = (const float*)d_in[6];
  const float* wv = (const float*)d_in[7];
  const float* bv = (const float*)d_in[8];
  const float* wo = (const float*)d_in[9];
  const float* bo = (const float*)d_in[10];
  const float* lb = (const float*)d_in[11];

  const int M = 8192, N = 1024, K = 1024;
  const size_t REG = (size_t)M * N * 2;

  char* ws = (char*)d_ws;
  bf16_t* Qb = (bf16_t*)(ws + 0 * REG);
  bf16_t* Kb = (bf16_t*)(ws + 1 * REG);
  bf16_t* Vt = (bf16_t*)(ws + 2 * REG);
  bf16_t* attn = (bf16_t*)(ws + 3 * REG);
  bf16_t* Wqb = (bf16_t*)(ws + 4 * REG);
  bf16_t* Wkb = Wqb + (size_t)N * K;
  bf16_t* Wvb = Wkb + (size_t)N * K;
  bf16_t* Wob = Wvb + (size_t)N * K;

  cvt4_kernel<<<dim3(512), dim3(256), 0, stream>>>(
      wq, wk, wv, wo, Wqb, Wkb, Wvb, Wob);

  gemm_qkv<<<dim3(N / GBN, M / GBM, 3), 256, 0, stream>>>(
      q32, k32, v32, Wqb, Wkb, Wvb, bq, bk, bv, Qb, Kb, Vt, M, N, K);

  attn_kernel<<<dim3(64, 2048 / QT), 256, 0, stream>>>(Qb, Kb, Vt, lb, attn);

  gemm_o<<<dim3(M / GBM, N / GBN), 256, 0, stream>>>(attn, Wob, bo, (float*)d_out, M, N, K);
}

// Round 20
// 195.492 us; speedup vs baseline: 2.5746x; 1.3805x over previous
//
#include <hip/hip_runtime.h>
#include <hip/hip_bf16.h>
#include <stdint.h>

typedef __bf16 bf16_t;
typedef bf16_t bf16x8 __attribute__((ext_vector_type(8)));
typedef bf16_t bf16x4 __attribute__((ext_vector_type(4)));
typedef float f32x4 __attribute__((ext_vector_type(4)));

#define LOG2E 1.44269504088896340736f

// async global->LDS, 16B per lane. Dest must be linear (base + lane*16).
__device__ __forceinline__ void gld16(const void* g, void* l) {
  __builtin_amdgcn_global_load_lds(
      (__attribute__((address_space(1))) void*)(void*)(g),
      (__attribute__((address_space(3))) void*)(l), 16, 0, 0);
}

// XOR swizzle for 128B-row LDS tiles: spreads the 16B column slots across rows.
__device__ __forceinline__ int swz(int byteoff) {
  return byteoff ^ (((byteoff >> 7) & 7) << 4);
}

// ---------------- fp32 -> bf16 convert: ALL 7 tensors in one launch ----------
__global__ __launch_bounds__(256) void cvt7_kernel(
    const float* __restrict__ a0, const float* __restrict__ a1, const float* __restrict__ a2,
    const float* __restrict__ w0, const float* __restrict__ w1,
    const float* __restrict__ w2, const float* __restrict__ w3,
    bf16_t* __restrict__ e0, bf16_t* __restrict__ e1, bf16_t* __restrict__ e2,
    bf16_t* __restrict__ f0, bf16_t* __restrict__ f1,
    bf16_t* __restrict__ f2, bf16_t* __restrict__ f3) {
  const float* s;
  bf16_t* d;
  int i, stride;
  if (blockIdx.x < 3072) {
    const int t = blockIdx.x >> 10;
    s = (t == 0) ? a0 : ((t == 1) ? a1 : a2);
    d = (t == 0) ? e0 : ((t == 1) ? e1 : e2);
    i = (blockIdx.x & 1023) * 256 + threadIdx.x;
    stride = 1024 * 256;
  } else {
    const int b = blockIdx.x - 3072;
    const int t = b >> 7;
    s = (t == 0) ? w0 : ((t == 1) ? w1 : ((t == 2) ? w2 : w3));
    d = (t == 0) ? f0 : ((t == 1) ? f1 : ((t == 2) ? f2 : f3));
    i = (b & 127) * 256 + threadIdx.x;
    stride = 128 * 256;
  }
#pragma unroll
  for (int u = 0; u < 8; ++u, i += stride) {
    const float4 v = reinterpret_cast<const float4*>(s)[i];
    bf16x4 o;
    o[0] = (bf16_t)v.x; o[1] = (bf16_t)v.y; o[2] = (bf16_t)v.z; o[3] = (bf16_t)v.w;
    reinterpret_cast<bf16x4*>(d)[i] = o;
  }
}

// ---------------- GEMM core: BK=64, double-buffered LDS, 2-phase (T3-min) ----
#define GBM 128
#define GBN 128
#define GBK 64

__device__ __forceinline__ void gemm_core(
    const bf16_t* __restrict__ A, const bf16_t* __restrict__ W,
    bf16_t* As, bf16_t* Bs, int m0, int n0, int K,
    int wm, int wn, int rr, int kk8, f32x4 acc[4][4]) {
  const int tid = threadIdx.x;
  const int t16 = tid * 16;
  int srow[4], scb[4];
#pragma unroll
  for (int i = 0; i < 4; ++i) {
    const int so = swz(i * 4096 + t16);
    srow[i] = so >> 7;   // tile row 0..127
    scb[i] = so & 127;   // byte within 128B row
  }
  const char* Ab = (const char*)A;
  const char* Wb = (const char*)W;
  const int nk = K / GBK;

#define GSTAGE(bufsel, kk0)                                                    \
  {                                                                            \
    char* Al = (char*)As + (bufsel) * 16384 + t16;                             \
    char* Bl = (char*)Bs + (bufsel) * 16384 + t16;                             \
    _Pragma("unroll")                                                          \
    for (int i = 0; i < 4; ++i) {                                              \
      gld16(Ab + ((size_t)(m0 + srow[i]) * K + (kk0)) * 2 + scb[i], Al + i * 4096); \
      gld16(Wb + ((size_t)(n0 + srow[i]) * K + (kk0)) * 2 + scb[i], Bl + i * 4096); \
    }                                                                          \
  }

  GSTAGE(0, 0)
  for (int t = 0; t < nk; ++t) {
    const int b = t & 1;
    asm volatile("s_waitcnt vmcnt(0)" ::: "memory");
    __builtin_amdgcn_s_barrier();
    __builtin_amdgcn_sched_barrier(0);
    GSTAGE(b ^ 1, ((t + 1) & (nk - 1)) * GBK)
    const char* Abl = (const char*)As + b * 16384;
    const char* Bbl = (const char*)Bs + b * 16384;
#pragma unroll
    for (int kk = 0; kk < 2; ++kk) {
      bf16x8 a[4], bb[4];
#pragma unroll
      for (int i = 0; i < 4; ++i)
        a[i] = *reinterpret_cast<const bf16x8*>(
            Abl + swz((wm + i * 16 + rr) * 128 + (kk * 32 + kk8) * 2));
#pragma unroll
      for (int i = 0; i < 4; ++i)
        bb[i] = *reinterpret_cast<const bf16x8*>(
            Bbl + swz((wn + i * 16 + rr) * 128 + (kk * 32 + kk8) * 2));
      __builtin_amdgcn_s_setprio(1);
#pragma unroll
      for (int i = 0; i < 4; ++i)
#pragma unroll
        for (int j = 0; j < 4; ++j)
          acc[i][j] = __builtin_amdgcn_mfma_f32_16x16x32_bf16(a[i], bb[j], acc[i][j], 0, 0, 0);
      __builtin_amdgcn_s_setprio(0);
    }
  }
#undef GSTAGE
}

// ---------------- fused Q/K/V projection GEMMs (blockIdx.z selects) --------
__global__ __launch_bounds__(256) void gemm_qkv(
    const bf16_t* __restrict__ Xq, const bf16_t* __restrict__ Xk, const bf16_t* __restrict__ Xv,
    const bf16_t* __restrict__ Wq, const bf16_t* __restrict__ Wk, const bf16_t* __restrict__ Wv,
    const float* __restrict__ bq, const float* __restrict__ bk, const float* __restrict__ bv,
    bf16_t* __restrict__ Qo, bf16_t* __restrict__ Ko, bf16_t* __restrict__ Vo,
    int M, int N, int K) {
  const int z = blockIdx.z;
  const bf16_t* A = (z == 0) ? Xq : ((z == 1) ? Xk : Xv);
  const bf16_t* W = (z == 0) ? Wq : ((z == 1) ? Wk : Wv);
  const float* bias = (z == 0) ? bq : ((z == 1) ? bk : bv);
  bf16_t* Out = (z == 0) ? Qo : ((z == 1) ? Ko : Vo);

  __shared__ bf16_t As[2 * GBM * GBK];  // 32KB
  __shared__ bf16_t Bs[2 * GBN * GBK];  // 32KB
  const int tid = threadIdx.x;
  const int lane = tid & 63;
  const int w = tid >> 6;
  const int m0 = blockIdx.x * GBM;
  const int n0 = blockIdx.y * GBN;
  const int wm = (w >> 1) * 64;
  const int wn = (w & 1) * 64;
  const int rr = lane & 15;
  const int kk8 = (lane >> 4) * 8;

  f32x4 acc[4][4] = {};
  gemm_core(A, W, As, Bs, m0, n0, K, wm, wn, rr, kk8, acc);

  const int rg = (lane >> 4) * 4;
#pragma unroll
  for (int i = 0; i < 4; ++i) {
#pragma unroll
    for (int j = 0; j < 4; ++j) {
      const int col = n0 + wn + j * 16 + rr;
      const float bi = bias[col];
      if (z == 2) {
        const int row0 = m0 + wm + i * 16 + rg;
        const int b_ = row0 >> 11, s_ = row0 & 2047;
        const int h_ = col >> 6, d_ = col & 63;
        const int k64 = s_ & 63;
        const int sl = (k64 & 32) | ((k64 & 12) << 1) | ((k64 & 16) >> 2);
        const int scol = (s_ & ~63) | sl;
        bf16x4 pack;
#pragma unroll
        for (int r = 0; r < 4; ++r) pack[r] = (bf16_t)(acc[i][j][r] + bi);
        *reinterpret_cast<bf16x4*>(&Out[((size_t)((b_ * 16 + h_) * 64 + d_)) * 2048 + scol]) = pack;
      } else {
        const float scale = (z == 0) ? (0.125f * LOG2E) : 1.0f;
#pragma unroll
        for (int r = 0; r < 4; ++r) {
          const int row = m0 + wm + i * 16 + rg + r;
          const int b_ = row >> 11, s_ = row & 2047;
          const int h_ = col >> 6, d_ = col & 63;
          Out[((size_t)((b_ * 16 + h_) * 2048 + s_)) * 64 + d_] = (bf16_t)((acc[i][j][r] + bi) * scale);
        }
      }
    }
  }
}

// ---------------- output projection GEMM: fp32 out ----------------
__global__ __launch_bounds__(256) void gemm_o(
    const bf16_t* __restrict__ A, const bf16_t* __restrict__ W,
    const float* __restrict__ bias, float* __restrict__ Out,
    int M, int N, int K) {
  __shared__ bf16_t As[2 * GBM * GBK];
  __shared__ bf16_t Bs[2 * GBN * GBK];
  const int tid = threadIdx.x;
  const int lane = tid & 63;
  const int w = tid >> 6;
  const int m0 = blockIdx.x * GBM;
  const int n0 = blockIdx.y * GBN;
  const int wm = (w >> 1) * 64;
  const int wn = (w & 1) * 64;
  const int rr = lane & 15;
  const int kk8 = (lane >> 4) * 8;

  f32x4 acc[4][4] = {};
  gemm_core(A, W, As, Bs, m0, n0, K, wm, wn, rr, kk8, acc);

  const int rg = (lane >> 4) * 4;
#pragma unroll
  for (int i = 0; i < 4; ++i)
#pragma unroll
    for (int j = 0; j < 4; ++j) {
      const int col = n0 + wn + j * 16 + rr;
      const float bi = bias[col];
#pragma unroll
      for (int r = 0; r < 4; ++r) {
        const int row = m0 + wm + i * 16 + rg + r;
        Out[(size_t)row * N + col] = acc[i][j][r] + bi;
      }
    }
}

// ---------------- flash attention with banded local bias ----------------
// v13 frozen (90.5us): v9 structure + __builtin_amdgcn_exp2f, (256,2) cap.
#define QT 256
#define KT 64

__global__ __launch_bounds__(256, 2) void attn_kernel(
    const bf16_t* __restrict__ Qg, const bf16_t* __restrict__ Kg,
    const bf16_t* __restrict__ Vtg, const float* __restrict__ lb,
    bf16_t* __restrict__ Og) {
  const int S = 2048;
  __shared__ bf16_t Qs[QT * 64];   // 32KB, swizzled (prologue only)
  __shared__ bf16_t Ks[KT * 64];   // 8KB, swizzled
  __shared__ bf16_t Vts[64 * KT];  // 8KB, swizzled (rows=d, cols=k-slots)
  __shared__ float lbs[33];

  const int tid = threadIdx.x, lane = tid & 63, w = tid >> 6;
  const int bh = blockIdx.x;          // fast dim -> same-bh blocks same XCD
  const int qt0 = blockIdx.y * QT;
  const int b_ = bh >> 4, h_ = bh & 15;

  const char* Qb = (const char*)(Qg + (size_t)bh * S * 64);
  const char* Kb = (const char*)(Kg + (size_t)bh * S * 64);
  const char* Vtb = (const char*)(Vtg + (size_t)bh * 64 * S);

  // stage Q tile: 32KB = 8 issues x 256 threads x 16B
#pragma unroll
  for (int i = 0; i < 8; ++i) {
    const int off = i * 4096 + tid * 16;
    gld16(Qb + (size_t)qt0 * 128 + swz(off), (char*)Qs + off);
  }
  if (tid < 33) lbs[tid] = lb[tid];

  // K/V reg staging (T14), write-side swizzle
  const int L0 = tid * 16;                   // 0..4095
  const int W0 = swz(L0), W1 = swz(L0 + 4096);
  const int vd0 = L0 >> 7, vcb = L0 & 127;
  int4 kr0, kr1, vr0, vr1;

#define LOADKV(t)                                                              \
  {                                                                            \
    const char* kp = Kb + (size_t)(t) * 8192;                                  \
    kr0 = *reinterpret_cast<const int4*>(kp + L0);                             \
    kr1 = *reinterpret_cast<const int4*>(kp + L0 + 4096);                      \
    const char* vp = Vtb + (size_t)(t) * 128;                                  \
    vr0 = *reinterpret_cast<const int4*>(vp + (size_t)vd0 * 4096 + vcb);       \
    vr1 = *reinterpret_cast<const int4*>(vp + (size_t)(vd0 + 32) * 4096 + vcb);\
  }
#define WRITEKV()                                                              \
  {                                                                            \
    *reinterpret_cast<int4*>((char*)Ks + W0) = kr0;                            \
    *reinterpret_cast<int4*>((char*)Ks + W1) = kr1;                            \
    *reinterpret_cast<int4*>((char*)Vts + W0) = vr0;                           \
    *reinterpret_cast<int4*>((char*)Vts + W1) = vr1;                           \
  }

  LOADKV(0)
  __syncthreads();  // Q staged (drains gld16)

  const int rr = lane & 15;
  const int kk8 = (lane >> 4) * 8;
  const int rg = (lane >> 4) * 4;

  bf16x8 qf[4][2];  // wave w owns q rows [w*64, w*64+64)
#pragma unroll
  for (int qg = 0; qg < 4; ++qg)
#pragma unroll
    for (int kk = 0; kk < 2; ++kk) {
      const int off = (w * 64 + qg * 16 + rr) * 128 + (kk * 32 + kk8) * 2;
      qf[qg][kk] = *reinterpret_cast<const bf16x8*>((const char*)Qs + swz(off));
    }

  f32x4 oacc[4][4] = {};
  float lrowp[4] = {0.f, 0.f, 0.f, 0.f};

  for (int kt = 0; kt < S / KT; ++kt) {
    // commit staged tile kt (regs loaded last iter, drained at last barrier)
    WRITEKV()
    __syncthreads();  // tile kt visible
    // prefetch tile kt+1: issued AFTER the barrier -> overlaps compute,
    // drained by the end-of-iteration barrier's vmcnt(0)
    LOADKV((kt + 1) & 31)

    bf16x8 kf[4][2];
#pragma unroll
    for (int ni = 0; ni < 4; ++ni)
#pragma unroll
      for (int kk = 0; kk < 2; ++kk) {
        const int off = (ni * 16 + rr) * 128 + (kk * 32 + kk8) * 2;
        kf[ni][kk] = *reinterpret_cast<const bf16x8*>((const char*)Ks + swz(off));
      }
    bf16x8 vf[2][4];
#pragma unroll
    for (int kk = 0; kk < 2; ++kk)
#pragma unroll
      for (int nd = 0; nd < 4; ++nd) {
        const int off = (nd * 16 + rr) * 128 + (kk * 32 + kk8) * 2;
        vf[kk][nd] = *reinterpret_cast<const bf16x8*>((const char*)Vts + swz(off));
      }

    const int kbase = kt * KT;
#pragma unroll
    for (int qg = 0; qg < 4; ++qg) {
      // QK^T (swapped): lane holds q = w*64 + qg*16 + rr; k = 16ni + 4hi + r
      f32x4 sc[4];
      __builtin_amdgcn_s_setprio(1);
#pragma unroll
      for (int ni = 0; ni < 4; ++ni) {
        f32x4 z = {0.f, 0.f, 0.f, 0.f};
#pragma unroll
        for (int kk = 0; kk < 2; ++kk)
          z = __builtin_amdgcn_mfma_f32_16x16x32_bf16(kf[ni][kk], qf[qg][kk], z, 0, 0, 0);
        sc[ni] = z;
      }
      __builtin_amdgcn_s_setprio(0);

      // banded local bias (exp2 domain); wave-uniform guard per qg
      const int qlo = qt0 + w * 64 + qg * 16;
      if (kbase + KT + 16 > qlo && kbase < qlo + 16 + 16) {
        const int q = qlo + rr;
#pragma unroll
        for (int ni = 0; ni < 4; ++ni)
#pragma unroll
          for (int r = 0; r < 4; ++r) {
            const int rel = (kbase + ni * 16 + rg + r) - q;
            if (rel >= -16 && rel <= 16)
              sc[ni][r] += (2.0f * LOG2E) * lbs[rel + 16];
          }
      }

      // softmax (no max subtraction; scores bounded) + PV A-frags in-register
      bf16x8 paf[2];
      float ps0 = 0.f, ps1 = 0.f;
#pragma unroll
      for (int ni = 0; ni < 4; ++ni) {
        const float p0 = __builtin_amdgcn_exp2f(sc[ni][0]);
        const float p1 = __builtin_amdgcn_exp2f(sc[ni][1]);
        const float p2 = __builtin_amdgcn_exp2f(sc[ni][2]);
        const float p3 = __builtin_amdgcn_exp2f(sc[ni][3]);
        ps0 += p0 + p2;
        ps1 += p1 + p3;
        paf[ni >> 1][(ni & 1) * 4 + 0] = (bf16_t)p0;
        paf[ni >> 1][(ni & 1) * 4 + 1] = (bf16_t)p1;
        paf[ni >> 1][(ni & 1) * 4 + 2] = (bf16_t)p2;
        paf[ni >> 1][(ni & 1) * 4 + 3] = (bf16_t)p3;
      }
      lrowp[qg] += ps0 + ps1;

      // PV (V slot-permuted to match A-frag slots)
      __builtin_amdgcn_s_setprio(1);
#pragma unroll
      for (int kk = 0; kk < 2; ++kk)
#pragma unroll
        for (int nd = 0; nd < 4; ++nd)
          oacc[qg][nd] = __builtin_amdgcn_mfma_f32_16x16x32_bf16(paf[kk], vf[kk][nd], oacc[qg][nd], 0, 0, 0);
      __builtin_amdgcn_s_setprio(0);
    }
    __syncthreads();  // readers done with Ks/Vts; prefetch loads drained
  }

  // epilogue
#pragma unroll
  for (int qg = 0; qg < 4; ++qg) {
    float t = lrowp[qg];
    t += __shfl_xor(t, 16, 64);
    t += __shfl_xor(t, 32, 64);
    float lf[4];
#pragma unroll
    for (int r = 0; r < 4; ++r)
      lf[r] = __shfl(t, (lane & 48) | (rg + r), 64);
#pragma unroll
    for (int nd = 0; nd < 4; ++nd)
#pragma unroll
      for (int r = 0; r < 4; ++r) {
        const int srow = qt0 + w * 64 + qg * 16 + rg + r;
        const int d = nd * 16 + rr;
        const float v = oacc[qg][nd][r] / lf[r];
        Og[((size_t)(b_ * 2048 + srow)) * 1024 + h_ * 64 + d] = (bf16_t)v;
      }
  }
}

// ---------------- launch ----------------
extern "C" void kernel_launch(void* const* d_in, const int* in_sizes, int n_in,
                              void* d_out, int out_size, void* d_ws, size_t ws_size,
                              hipStream_t stream) {
  const float* q32 = (const float*)d_in[0];
  const float* k32 = (const float*)d_in[1];
  const float* v32 = (const float*)d_in[2];
  const float* wq = (const float*)d_in[3];
  const float* bq = (const float*)d_in[4];
  const float* wk = (const float*)d_in[5];
  const float* bk = (const float*)d_in[6];
  const float* wv = (const float*)d_in[7];
  const float* bv = (const float*)d_in[8];
  const float* wo = (const float*)d_in[9];
  const float* bo = (const float*)d_in[10];
  const float* lb = (const float*)d_in[11];

  const int M = 8192, N = 1024, K = 1024;
  const size_t REG = (size_t)M * N * 2;

  char* ws = (char*)d_ws;
  bf16_t* Xq = (bf16_t*)(ws + 0 * REG);
  bf16_t* Xk = (bf16_t*)(ws + 1 * REG);
  bf16_t* Xv = (bf16_t*)(ws + 2 * REG);
  bf16_t* Qb = (bf16_t*)(ws + 3 * REG);
  bf16_t* Wqb = (bf16_t*)(ws + 4 * REG);
  bf16_t* Wkb = Wqb + (size_t)N * K;
  bf16_t* Wvb = Wkb + (size_t)N * K;
  bf16_t* Wob = Wvb + (size_t)N * K;
  bf16_t* Kb = Xq;    // Xq dead after Q-GEMM
  bf16_t* Vt = Xk;    // Xk dead after K-GEMM
  bf16_t* attn = Xv;  // Xv dead after V-GEMM

  cvt7_kernel<<<dim3(3584), dim3(256), 0, stream>>>(
      q32, k32, v32, wq, wk, wv, wo, Xq, Xk, Xv, Wqb, Wkb, Wvb, Wob);

  gemm_qkv<<<dim3(M / GBM, N / GBN, 3), 256, 0, stream>>>(
      Xq, Xk, Xv, Wqb, Wkb, Wvb, bq, bk, bv, Qb, Kb, Vt, M, N, K);

  attn_kernel<<<dim3(64, 2048 / QT), 256, 0, stream>>>(Qb, Kb, Vt, lb, attn);

  gemm_o<<<dim3(M / GBM, N / GBN), 256, 0, stream>>>(attn, Wob, bo, (float*)d_out, M, N, K);
}